// Round 1
// baseline (153.317 us; speedup 1.0000x reference)
//
#include <hip/hip_runtime.h>

#define HH 1024
#define WW 1024
#define BB 8
#define TILE 64
#define HALO 5
#define TW (TILE + 2*HALO)   /* 74 */

// Fused kernel: edge detection (separable 11x11 integer window sum via LDS)
// + log_softmax(C=2) + masked loss, block-reduced, atomic double accumulate.
__global__ __launch_bounds__(256) void ls_main(const float* __restrict__ x,
                                               const int* __restrict__ tgt,
                                               double* __restrict__ acc_out) {
    __shared__ int s_t[TW * TW];      // target tile + halo (zero-padded OOB)
    __shared__ int s_h[TW * TILE];    // horizontal 11-sums
    __shared__ float s_red[4];

    const int tid = threadIdx.x;
    const int b  = blockIdx.z;
    const int ty = blockIdx.y * TILE;
    const int tx = blockIdx.x * TILE;
    const int ty0 = ty - HALO;
    const int tx0 = tx - HALO;

    const int* tb = tgt + (size_t)b * HH * WW;

    // Phase A: stage target tile + halo into LDS (zero padding outside image).
    for (int i = tid; i < TW * TW; i += 256) {
        int r = i / TW;
        int c = i - r * TW;
        int gy = ty0 + r, gx = tx0 + c;
        int v = 0;
        if ((unsigned)gy < HH && (unsigned)gx < WW) v = tb[gy * WW + gx];
        s_t[i] = v;
    }
    __syncthreads();

    // Phase B: horizontal 11-sums for all 74 rows x 64 cols.
    for (int i = tid; i < TW * TILE; i += 256) {
        int r = i >> 6, c = i & 63;
        int base = r * TW + c;
        int s = 0;
#pragma unroll
        for (int k = 0; k < 11; ++k) s += s_t[base + k];
        s_h[i] = s;
    }
    __syncthreads();

    const float* x0p = x + ((size_t)b * 2 + 0) * HH * WW;
    const float* x1p = x + ((size_t)b * 2 + 1) * HH * WW;

    // Phase C: vertical 11-sums -> edge; log_softmax; masked loss.
    const int col = tid & 63;   // wave covers one full row -> coalesced x loads
    const int rb  = tid >> 6;
    float acc = 0.f;
#pragma unroll 4
    for (int j = 0; j < 16; ++j) {
        int row = rb + j * 4;
        int gy = ty + row, gx = tx + col;
        int S = 0;
#pragma unroll
        for (int k = 0; k < 11; ++k) S += s_h[(row + k) * TILE + col];
        int t = s_t[(row + HALO) * TW + (col + HALO)];
        // conv = 121*t_center - S ; edge = (conv != 0)  (exact in int)
        bool edge = (121 * t != S);

        float xv0 = x0p[(size_t)gy * WW + gx];
        float xv1 = x1p[(size_t)gy * WW + gx];
        float m   = fmaxf(xv0, xv1);
        float lse = m + log1pf(__expf(-fabsf(xv0 - xv1)));
        float lp0 = xv0 - lse, lp1 = xv1 - lse;
        float lpt = t ? lp1 : lp0;
        float lpo = t ? lp0 : lp1;
        acc += edge ? (0.95f * lpt + 0.1f * lpo) : lpt;
    }

    // Wave (64-lane) reduce, then cross-wave via LDS, one double atomic/block.
#pragma unroll
    for (int off = 32; off > 0; off >>= 1) acc += __shfl_down(acc, off, 64);
    if ((tid & 63) == 0) s_red[tid >> 6] = acc;
    __syncthreads();
    if (tid == 0) {
        float bs = s_red[0] + s_red[1] + s_red[2] + s_red[3];
        atomicAdd(acc_out, (double)bs);
    }
}

__global__ void ls_final(const double* __restrict__ acc, float* __restrict__ out) {
    out[0] = (float)(-acc[0] * (1.0 / (8.0 * 1024.0 * 1024.0)));
}

extern "C" void kernel_launch(void* const* d_in, const int* in_sizes, int n_in,
                              void* d_out, int out_size, void* d_ws, size_t ws_size,
                              hipStream_t stream) {
    const float* x  = (const float*)d_in[0];
    const int* tgt  = (const int*)d_in[1];
    double* acc     = (double*)d_ws;

    hipMemsetAsync(d_ws, 0, sizeof(double), stream);  // zero the accumulator (ws is poisoned)
    dim3 grid(WW / TILE, HH / TILE, BB);
    hipLaunchKernelGGL(ls_main, grid, dim3(256), 0, stream, x, tgt, acc);
    hipLaunchKernelGGL(ls_final, dim3(1), dim3(1), 0, stream, acc, (float*)d_out);
}

// Round 2
// 142.104 us; speedup vs baseline: 1.0789x; 1.0789x over previous
//
#include <hip/hip_runtime.h>

#define HH 1024
#define WW 1024
#define BB 8
#define TILE 64
#define HALO 5
#define TROWS 74            /* TILE + 2*HALO                    */
#define TB    76            /* byte pitch of target tile (pad)  */
#define TD    19            /* dword pitch = TB/4               */
#define HP    65            /* s_h row pitch (pad +1: no bank conflict) */

// Fused: 11x11 edge detect (separable int window sums, sliding-window in both
// directions) + log_softmax(C=2) + smoothed-mask loss, double-atomic reduce.
__global__ __launch_bounds__(256) void ls_main(const float* __restrict__ x,
                                               const int* __restrict__ tgt,
                                               double* __restrict__ acc_out) {
    __shared__ int s_t[TROWS * TD];     // target tile, 1 byte/px, packed dwords
    __shared__ int s_h[TROWS * HP];     // horizontal 11-sums, padded pitch 65
    __shared__ float s_red[4];
    unsigned char* s_tb = (unsigned char*)s_t;

    const int tid = threadIdx.x;
    const int b  = blockIdx.z;
    const int ty = blockIdx.y * TILE;
    const int tx = blockIdx.x * TILE;
    const int ty0 = ty - HALO;
    const int tx0 = tx - HALO;

    const int* tb_g = tgt + (size_t)b * HH * WW;

    // Phase A: stage target tile+halo as bytes (packed 4/dword), zero-pad OOB.
    for (int d = tid; d < TROWS * TD; d += 256) {
        int r = d / TD;
        int dc = d - r * TD;
        int gy = ty0 + r;
        int c0 = dc * 4;             // byte col of first element
        unsigned int pk = 0;
        if ((unsigned)gy < HH) {
#pragma unroll
            for (int bnum = 0; bnum < 4; ++bnum) {
                int c = c0 + bnum;
                int gx = tx0 + c;
                if (c < TROWS && (unsigned)gx < WW)
                    pk |= ((unsigned int)tb_g[gy * WW + gx]) << (8 * bnum);
            }
        }
        s_t[d] = (int)pk;
    }
    __syncthreads();

    // Phase B: horizontal 11-sums, sliding window. 222 threads: 3 col-segments
    // per row (22/22/20 cols).
    if (tid < 222) {
        int row = tid / 3;
        int seg = tid - row * 3;
        int cbeg = seg * 22;
        int cend = (seg == 2) ? 64 : cbeg + 22;
        int base = row * TB + cbeg;
        int W = 0;
#pragma unroll
        for (int k = 0; k < 11; ++k) W += s_tb[base + k];
        int hb = row * HP;
        for (int c = cbeg; c < cend; ++c) {
            s_h[hb + c] = W;
            // slide; c+11 may touch the zero-pad bytes (cols 74/75) harmlessly
            W += (int)s_tb[row * TB + c + 11] - (int)s_tb[row * TB + c];
        }
    }
    __syncthreads();

    const float* x0p = x + ((size_t)b * 2 + 0) * HH * WW;
    const float* x1p = x + ((size_t)b * 2 + 1) * HH * WW;

    // Phase C: vertical sliding window; thread = (col, 16 consecutive rows).
    const int col   = tid & 63;
    const int chunk = tid >> 6;
    const int r0    = chunk * 16;

    int V = 0;
#pragma unroll
    for (int k = 0; k < 11; ++k) V += s_h[(r0 + k) * HP + col];

    float acc = 0.f;
#pragma unroll
    for (int j = 0; j < 16; ++j) {
        int row = r0 + j;
        int t = s_tb[(row + HALO) * TB + (col + HALO)];
        bool edge = (121 * t != V);          // conv = 121*t_center - W ; exact
        if (j != 15)
            V += s_h[(row + 11) * HP + col] - s_h[row * HP + col];

        size_t gidx = (size_t)(ty + row) * WW + (tx + col);
        float xv0 = x0p[gidx];
        float xv1 = x1p[gidx];
        float m   = fmaxf(xv0, xv1);
        float lse = m + __logf(1.0f + __expf(-fabsf(xv0 - xv1)));
        float lp0 = xv0 - lse, lp1 = xv1 - lse;
        float lpt = t ? lp1 : lp0;
        float lpo = t ? lp0 : lp1;
        acc += edge ? (0.95f * lpt + 0.1f * lpo) : lpt;
    }

    // Wave(64) shuffle reduce -> cross-wave LDS -> one double atomic per block.
#pragma unroll
    for (int off = 32; off > 0; off >>= 1) acc += __shfl_down(acc, off, 64);
    if ((tid & 63) == 0) s_red[tid >> 6] = acc;
    __syncthreads();
    if (tid == 0) {
        float bs = s_red[0] + s_red[1] + s_red[2] + s_red[3];
        atomicAdd(acc_out, (double)bs);
    }
}

__global__ void ls_final(const double* __restrict__ acc, float* __restrict__ out) {
    out[0] = (float)(-acc[0] * (1.0 / (8.0 * 1024.0 * 1024.0)));
}

extern "C" void kernel_launch(void* const* d_in, const int* in_sizes, int n_in,
                              void* d_out, int out_size, void* d_ws, size_t ws_size,
                              hipStream_t stream) {
    const float* x  = (const float*)d_in[0];
    const int* tgt  = (const int*)d_in[1];
    double* acc     = (double*)d_ws;

    hipMemsetAsync(d_ws, 0, sizeof(double), stream);
    dim3 grid(WW / TILE, HH / TILE, BB);
    hipLaunchKernelGGL(ls_main, grid, dim3(256), 0, stream, x, tgt, acc);
    hipLaunchKernelGGL(ls_final, dim3(1), dim3(1), 0, stream, acc, (float*)d_out);
}

// Round 3
// 125.978 us; speedup vs baseline: 1.2170x; 1.1280x over previous
//
#include <hip/hip_runtime.h>

#define HH 1024
#define WW 1024
#define BB 8
#define TILE 64
#define HALO 5
#define TROWS 74           /* TILE + 2*HALO target rows staged            */
#define TB    80           /* byte pitch of target tile (8-col left halo) */
#define VP    65           /* s_v pitch over rows (pad +1)                */
#define NBLK  (16*16*8)    /* 2048 blocks                                 */

// Fused: 11x11 edge detect (vertical int sums in LDS, horizontal slide in
// registers) + log_softmax(C=2) + smoothed-mask loss. x prefetched to
// registers BEFORE the LDS phases so HBM latency hides behind setup.
__global__ __launch_bounds__(256) void ls_main(const float* __restrict__ x,
                                               const int* __restrict__ tgt,
                                               float* __restrict__ partial) {
    __shared__ int   s_t[TROWS * (TB / 4)];   // target bytes, packed dwords
    __shared__ int   s_v[74 * VP];            // vertical 11-sums [col][row]
    __shared__ float s_red[4];
    unsigned char* s_tb = (unsigned char*)s_t;

    const int tid = threadIdx.x;
    const int b  = blockIdx.z;
    const int ty = blockIdx.y * TILE;
    const int tx = blockIdx.x * TILE;
    const int ty0 = ty - HALO;

    // ---- Prefetch x for this thread's 16 pixels (row, cols c0..c0+15) ----
    const int row = tid >> 2;
    const int c0  = (tid & 3) << 4;
    const float* x0p = x + ((size_t)b * 2 + 0) * HH * WW + (size_t)(ty + row) * WW + tx + c0;
    const float* x1p = x + ((size_t)b * 2 + 1) * HH * WW + (size_t)(ty + row) * WW + tx + c0;
    float4 xv0[4], xv1[4];
#pragma unroll
    for (int q = 0; q < 4; ++q) xv0[q] = ((const float4*)x0p)[q];
#pragma unroll
    for (int q = 0; q < 4; ++q) xv1[q] = ((const float4*)x1p)[q];
    const float* f0 = (const float*)xv0;
    const float* f1 = (const float*)xv1;

    const int* tb_g = tgt + (size_t)b * HH * WW;

    // ---- Phase A: stage target bytes (int4 loads, 4 px -> 1 dword) ----
    // Byte col c corresponds to global col tx-8+c; rows ty0..ty0+73.
    for (int i = tid; i < TROWS * (TB / 4); i += 256) {
        int r  = i / (TB / 4);
        int ch = i - r * (TB / 4);
        int gy  = ty0 + r;
        int gx0 = tx - 8 + ch * 4;
        unsigned int pk = 0;
        if ((unsigned)gy < HH) {
            if (gx0 >= 0 && gx0 + 3 < WW) {
                int4 v = *(const int4*)(tb_g + (size_t)gy * WW + gx0);
                pk = (unsigned)v.x | ((unsigned)v.y << 8) |
                     ((unsigned)v.z << 16) | ((unsigned)v.w << 24);
            } else {
#pragma unroll
                for (int k = 0; k < 4; ++k) {
                    int gx = gx0 + k;
                    if ((unsigned)gx < WW)
                        pk |= ((unsigned)tb_g[(size_t)gy * WW + gx]) << (8 * k);
                }
            }
        }
        s_t[i] = (int)pk;
    }
    __syncthreads();

    // ---- Phase B: vertical 11-sums for byte cols 3..76, output rows 0..63.
    // s_v[(cc-3)*VP + r] = sum_{k=0..10} t[r+k][cc]. 296 tasks, sliding.
    for (int i = tid; i < 296; i += 256) {
        int cc = 3 + (i >> 2);
        int r0 = (i & 3) << 4;
        int V = 0;
#pragma unroll
        for (int k = 0; k < 11; ++k) V += s_tb[(r0 + k) * TB + cc];
        int base = (cc - 3) * VP;
        for (int r = r0; r < r0 + 16; ++r) {
            s_v[base + r] = V;
            if (r != r0 + 15) V += (int)s_tb[(r + 11) * TB + cc] - (int)s_tb[r * TB + cc];
        }
    }
    __syncthreads();

    // ---- Phase C: horizontal slide in registers; 16 px per thread ----
    // Output col j: window sum W(j) = sum_{d=0..10} s_v[(j+d)*VP + row].
    int W = 0;
#pragma unroll
    for (int d = 0; d < 11; ++d) W += s_v[(c0 + d) * VP + row];

    // Center target bits: 16 bytes at s_tb[(row+5)*TB + c0+8], 8B-aligned.
    const unsigned long long* tp =
        (const unsigned long long*)(s_tb + (row + HALO) * TB + c0 + 8);
    unsigned long long tlo = tp[0], thi = tp[1];

    float acc = 0.f;
#pragma unroll
    for (int jj = 0; jj < 16; ++jj) {
        int t = (int)((jj < 8 ? (tlo >> (8 * jj)) : (thi >> (8 * (jj - 8)))) & 1);
        bool edge = (121 * t != W);          // conv = 121*t_center - W, exact
        if (jj != 15)
            W += s_v[(c0 + jj + 11) * VP + row] - s_v[(c0 + jj) * VP + row];

        float a0 = f0[jj], a1 = f1[jj];
        float m   = fmaxf(a0, a1);
        float lse = m + __logf(1.0f + __expf(-fabsf(a0 - a1)));
        float lp0 = a0 - lse, lp1 = a1 - lse;
        float lpt = t ? lp1 : lp0;
        float lpo = t ? lp0 : lp1;
        acc += edge ? (0.95f * lpt + 0.1f * lpo) : lpt;
    }

    // ---- Reduce: wave(64) shuffle -> LDS -> one partial per block ----
#pragma unroll
    for (int off = 32; off > 0; off >>= 1) acc += __shfl_down(acc, off, 64);
    if ((tid & 63) == 0) s_red[tid >> 6] = acc;
    __syncthreads();
    if (tid == 0) {
        int bid = (blockIdx.z * gridDim.y + blockIdx.y) * gridDim.x + blockIdx.x;
        partial[bid] = s_red[0] + s_red[1] + s_red[2] + s_red[3];
    }
}

__global__ __launch_bounds__(256) void ls_final(const float* __restrict__ partial,
                                                float* __restrict__ out) {
    __shared__ double s_red[4];
    const int tid = threadIdx.x;
    double s = 0.0;
    for (int i = tid; i < NBLK; i += 256) s += (double)partial[i];
#pragma unroll
    for (int off = 32; off > 0; off >>= 1) s += __shfl_down(s, off, 64);
    if ((tid & 63) == 0) s_red[tid >> 6] = s;
    __syncthreads();
    if (tid == 0) {
        double total = s_red[0] + s_red[1] + s_red[2] + s_red[3];
        out[0] = (float)(-total * (1.0 / (8.0 * 1024.0 * 1024.0)));
    }
}

extern "C" void kernel_launch(void* const* d_in, const int* in_sizes, int n_in,
                              void* d_out, int out_size, void* d_ws, size_t ws_size,
                              hipStream_t stream) {
    const float* x  = (const float*)d_in[0];
    const int* tgt  = (const int*)d_in[1];
    float* partial  = (float*)d_ws;   // 2048 floats, all written every call

    dim3 grid(WW / TILE, HH / TILE, BB);
    hipLaunchKernelGGL(ls_main, grid, dim3(256), 0, stream, x, tgt, partial);
    hipLaunchKernelGGL(ls_final, dim3(1), dim3(256), 0, stream, partial, (float*)d_out);
}

// Round 4
// 122.551 us; speedup vs baseline: 1.2510x; 1.0280x over previous
//
#include <hip/hip_runtime.h>

#define HH 1024
#define WW 1024
#define BB 8
#define TILE 64
#define HALO 5
#define TROWS 74           /* TILE + 2*HALO staged target rows          */
#define TD    20           /* s_t pitch in dwords (80 bytes/row)        */
#define SVP   80           /* s_v byte pitch per output row             */
#define NBLK  (16*16*8)

// Fused 11x11 edge detect + log_softmax(C=2) + smoothed loss.
// Phase B does packed-byte vertical sums (4 cols per dword op, sums<=11 so no
// cross-byte carry/borrow); phase C slides horizontally entirely in registers
// from two ds_read_b128. x is prefetched and PINNED in VGPRs via asm so the
// loads can't sink past the barriers.
__global__ __launch_bounds__(256, 6) void ls_main(const float* __restrict__ x,
                                                  const int* __restrict__ tgt,
                                                  float* __restrict__ partial) {
    __shared__ __align__(16) int s_t[TROWS * TD];            // 5920 B
    __shared__ __align__(16) unsigned char s_v[TILE * SVP];  // 5120 B
    __shared__ float s_red[4];
    unsigned char* s_tb = (unsigned char*)s_t;

    const int tid = threadIdx.x;
    const int b  = blockIdx.z;
    const int ty = blockIdx.y * TILE;
    const int tx = blockIdx.x * TILE;
    const int ty0 = ty - HALO;

    // ---- Issue x loads first (16 px per thread: one row, cols c0..c0+15) ----
    const int row = tid >> 2;
    const int c0  = (tid & 3) << 4;
    const float* x0p = x + ((size_t)b * 2 + 0) * HH * WW + (size_t)(ty + row) * WW + tx + c0;
    const float* x1p = x + ((size_t)b * 2 + 1) * HH * WW + (size_t)(ty + row) * WW + tx + c0;
    float4 xv0[4], xv1[4];
#pragma unroll
    for (int q = 0; q < 4; ++q) xv0[q] = ((const float4*)x0p)[q];
#pragma unroll
    for (int q = 0; q < 4; ++q) xv1[q] = ((const float4*)x1p)[q];

    const int* tb_g = tgt + (size_t)b * HH * WW;

    // ---- Phase A: stage target tile as bytes (byte col c = global tx-8+c) ----
    for (int i = tid; i < TROWS * TD; i += 256) {
        int r  = i / TD;
        int ch = i - r * TD;
        int gy  = ty0 + r;
        int gx0 = tx - 8 + ch * 4;
        unsigned int pk = 0;
        if ((unsigned)gy < HH) {
            if (gx0 >= 0 && gx0 + 3 < WW) {
                int4 v = *(const int4*)(tb_g + (size_t)gy * WW + gx0);
                pk = (unsigned)v.x | ((unsigned)v.y << 8) |
                     ((unsigned)v.z << 16) | ((unsigned)v.w << 24);
            } else {
#pragma unroll
                for (int k = 0; k < 4; ++k) {
                    int gx = gx0 + k;
                    if ((unsigned)gx < WW)
                        pk |= ((unsigned)tb_g[(size_t)gy * WW + gx]) << (8 * k);
                }
            }
        }
        s_t[i] = (int)pk;
    }

    // Pin x in VGPRs HERE: x loads were issued before the target loads, and
    // vmcnt returns in order, so materializing them now costs no extra wait —
    // but it stops the compiler sinking the loads past the barriers.
#pragma unroll
    for (int q = 0; q < 4; ++q) {
        asm volatile("" :: "v"(xv0[q].x), "v"(xv0[q].y), "v"(xv0[q].z), "v"(xv0[q].w));
        asm volatile("" :: "v"(xv1[q].x), "v"(xv1[q].y), "v"(xv1[q].z), "v"(xv1[q].w));
    }
    __syncthreads();

    // ---- Phase B: packed vertical 11-sums. Task = (dword col ch, 16 rows).
    // Each byte lane of V holds one column's sum (<=11): dword add/sub exact.
    if (tid < 80) {
        int ch = tid >> 2;
        int r0 = (tid & 3) << 4;
        int V = 0;
#pragma unroll
        for (int k = 0; k < 11; ++k) V += s_t[(r0 + k) * TD + ch];
        for (int r = r0; r < r0 + 16; ++r) {
            *(int*)(s_v + r * SVP + (ch << 2)) = V;
            if (r != r0 + 15) V += s_t[(r + 11) * TD + ch] - s_t[r * TD + ch];
        }
    }
    __syncthreads();

    // ---- Phase C: horizontal slide in registers ----
    // Output col j needs byte-cols j+3..j+13; this thread needs c0+3..c0+28,
    // covered by 32 contiguous bytes at s_v[row*SVP + c0] (16B-aligned).
    uint4 va = *(const uint4*)(s_v + row * SVP + c0);
    uint4 vb = *(const uint4*)(s_v + row * SVP + c0 + 16);
    unsigned char vbytes[32];
    *(uint4*)(vbytes)      = va;
    *(uint4*)(vbytes + 16) = vb;

    const unsigned long long* tp =
        (const unsigned long long*)(s_tb + (row + HALO) * SVP + c0 + 8);
    unsigned long long tlo = tp[0], thi = tp[1];

    int W = 0;
#pragma unroll
    for (int i = 3; i <= 13; ++i) W += vbytes[i];

    const float* f0 = (const float*)xv0;
    const float* f1 = (const float*)xv1;
    float acc = 0.f;
#pragma unroll
    for (int jj = 0; jj < 16; ++jj) {
        int t = (int)((jj < 8 ? (tlo >> (8 * jj)) : (thi >> (8 * (jj - 8)))) & 1);
        bool edge = (121 * t != W);          // conv = 121*t - windowsum, exact
        if (jj != 15) W += (int)vbytes[jj + 14] - (int)vbytes[jj + 3];

        float a0 = f0[jj], a1 = f1[jj];
        float m   = fmaxf(a0, a1);
        float lse = m + __logf(1.0f + __expf(-fabsf(a0 - a1)));
        float lp0 = a0 - lse, lp1 = a1 - lse;
        float lpt = t ? lp1 : lp0;
        float lpo = t ? lp0 : lp1;
        acc += edge ? (0.95f * lpt + 0.1f * lpo) : lpt;
    }

    // ---- Reduce: wave(64) shuffle -> LDS -> one float partial per block ----
#pragma unroll
    for (int off = 32; off > 0; off >>= 1) acc += __shfl_down(acc, off, 64);
    if ((tid & 63) == 0) s_red[tid >> 6] = acc;
    __syncthreads();
    if (tid == 0) {
        int bid = (blockIdx.z * gridDim.y + blockIdx.y) * gridDim.x + blockIdx.x;
        partial[bid] = s_red[0] + s_red[1] + s_red[2] + s_red[3];
    }
}

__global__ __launch_bounds__(256) void ls_final(const float* __restrict__ partial,
                                                float* __restrict__ out) {
    __shared__ double s_red[4];
    const int tid = threadIdx.x;
    double s = 0.0;
    for (int i = tid; i < NBLK; i += 256) s += (double)partial[i];
#pragma unroll
    for (int off = 32; off > 0; off >>= 1) s += __shfl_down(s, off, 64);
    if ((tid & 63) == 0) s_red[tid >> 6] = s;
    __syncthreads();
    if (tid == 0) {
        double total = s_red[0] + s_red[1] + s_red[2] + s_red[3];
        out[0] = (float)(-total * (1.0 / (8.0 * 1024.0 * 1024.0)));
    }
}

extern "C" void kernel_launch(void* const* d_in, const int* in_sizes, int n_in,
                              void* d_out, int out_size, void* d_ws, size_t ws_size,
                              hipStream_t stream) {
    const float* x  = (const float*)d_in[0];
    const int* tgt  = (const int*)d_in[1];
    float* partial  = (float*)d_ws;   // 2048 floats, all written every call

    dim3 grid(WW / TILE, HH / TILE, BB);
    hipLaunchKernelGGL(ls_main, grid, dim3(256), 0, stream, x, tgt, partial);
    hipLaunchKernelGGL(ls_final, dim3(1), dim3(256), 0, stream, partial, (float*)d_out);
}